// Round 2
// 1442.126 us; speedup vs baseline: 1.0012x; 1.0012x over previous
//
#include <hip/hip_runtime.h>
#include <hip/hip_bf16.h>
#include <stdint.h>

#define L_ 1024
#define B_ 4
#define D_ 1024
#define PROJ_ 256
#define H_ 8
#define V_ 32000
#define M_ 4096

typedef __bf16 bf16x8 __attribute__((ext_vector_type(8)));
typedef float f32x4 __attribute__((ext_vector_type(4)));

#define AS3(p) ((__attribute__((address_space(3))) void*)(p))
#define AS1(p) ((const __attribute__((address_space(1))) void*)(p))

// ---------------- embedding gather -> bf16 ----------------
__global__ __launch_bounds__(256) void k_embed(const int* __restrict__ x,
                                               const float* __restrict__ emb,
                                               __hip_bfloat16* __restrict__ h) {
  int gid = blockIdx.x * 256 + threadIdx.x;
  int row = gid >> 8;
  int d0 = (gid & 255) << 2;
  int tok = x[row];
  const float4 v = *(const float4*)(emb + (size_t)tok * D_ + d0);
  union { __hip_bfloat16 o[4]; uint2 u; } cv;
  cv.o[0] = __float2bfloat16(v.x);
  cv.o[1] = __float2bfloat16(v.y);
  cv.o[2] = __float2bfloat16(v.z);
  cv.o[3] = __float2bfloat16(v.w);
  *(uint2*)(h + (size_t)row * D_ + d0) = cv.u;
}

// ------------- transpose-convert: fp32 [K][N] -> bf16 [N][K], layer batched ---
__global__ __launch_bounds__(256) void k_transpose(const float* __restrict__ in,
                                                   __hip_bfloat16* __restrict__ out,
                                                   int K, int N,
                                                   long in_stride, long out_stride) {
  __shared__ float t[64][65];
  in += (size_t)blockIdx.z * in_stride;
  out += (size_t)blockIdx.z * out_stride;
  int n0 = blockIdx.x * 64, k0 = blockIdx.y * 64;
  int r = threadIdx.x >> 4, c4 = (threadIdx.x & 15) << 2;
#pragma unroll
  for (int p = 0; p < 4; p++) {
    float4 v = *(const float4*)(in + (size_t)(k0 + p * 16 + r) * N + n0 + c4);
    t[p * 16 + r][c4 + 0] = v.x;
    t[p * 16 + r][c4 + 1] = v.y;
    t[p * 16 + r][c4 + 2] = v.z;
    t[p * 16 + r][c4 + 3] = v.w;
  }
  __syncthreads();
  int n = threadIdx.x >> 2, kg = (threadIdx.x & 3) << 4;
  union { __hip_bfloat16 b[16]; uint4 u[2]; } cv;
#pragma unroll
  for (int i = 0; i < 16; i++) cv.b[i] = __float2bfloat16(t[kg + i][n]);
  uint4* op = (uint4*)(out + (size_t)(n0 + n) * K + k0 + kg);
  op[0] = cv.u[0];
  op[1] = cv.u[1];
}

// ------------- m97-style GEMM + XOR-swizzled LDS: A[M][K] bf16, Bt[N][K] bf16 ---
// (kept for the per-layer GEMMs; classifier moved to k_gemm_cls256)
template <bool CLS>
__global__ __launch_bounds__(256) void k_gemm_bt(
    const __hip_bfloat16* __restrict__ A, const __hip_bfloat16* __restrict__ Bt,
    __hip_bfloat16* __restrict__ C, int K, int N,
    const float* __restrict__ bout, const int* __restrict__ y,
    float2* __restrict__ lse, float* __restrict__ logitY) {
  __shared__ __hip_bfloat16 As[128 * 64];
  __shared__ __hip_bfloat16 Bs[128 * 64];
  const int tid = threadIdx.x;
  const int lane = tid & 63, wave = tid >> 6;
  const int quad = lane >> 4, l16 = lane & 15;
  const int wm = wave & 1, wn = wave >> 1;
  const int row0 = blockIdx.x * 128, col0 = blockIdx.y * 128;

  f32x4 acc[4][4] = {};

  const __hip_bfloat16* Abase = A + (size_t)row0 * K;
  const __hip_bfloat16* Bbase = Bt + (size_t)col0 * K;
  const int m_s = tid >> 3;
  const int ko_sw = (((tid & 7) ^ (m_s & 7)) << 3);
  const int xr = l16 & 7;

  for (int k0 = 0; k0 < K; k0 += 64) {
    __syncthreads();
#pragma unroll
    for (int call = 0; call < 4; call++) {
      int m = m_s + call * 32;
      __builtin_amdgcn_global_load_lds(AS1(Abase + (size_t)m * K + k0 + ko_sw),
                                       AS3(As + (call * 256 + wave * 64) * 8),
                                       16, 0, 0);
      __builtin_amdgcn_global_load_lds(AS1(Bbase + (size_t)m * K + k0 + ko_sw),
                                       AS3(Bs + (call * 256 + wave * 64) * 8),
                                       16, 0, 0);
    }
    __syncthreads();
#pragma unroll
    for (int kk = 0; kk < 2; kk++) {
      bf16x8 af[4], bfr[4];
#pragma unroll
      for (int mi = 0; mi < 4; mi++)
        af[mi] = *(const bf16x8*)(As + (wm * 64 + mi * 16 + l16) * 64 +
                                  (((kk * 4 + quad) ^ xr) << 3));
#pragma unroll
      for (int ni = 0; ni < 4; ni++)
        bfr[ni] = *(const bf16x8*)(Bs + (wn * 64 + ni * 16 + l16) * 64 +
                                   (((kk * 4 + quad) ^ xr) << 3));
#pragma unroll
      for (int mi = 0; mi < 4; mi++)
#pragma unroll
        for (int ni = 0; ni < 4; ni++)
          acc[mi][ni] = __builtin_amdgcn_mfma_f32_16x16x32_bf16(af[mi], bfr[ni],
                                                                acc[mi][ni], 0, 0, 0);
    }
  }

  if constexpr (!CLS) {
#pragma unroll
    for (int mi = 0; mi < 4; mi++)
#pragma unroll
      for (int ni = 0; ni < 4; ni++)
#pragma unroll
        for (int r = 0; r < 4; r++) {
          int row = row0 + wm * 64 + mi * 16 + quad * 4 + r;
          int col = col0 + wn * 64 + ni * 16 + l16;
          C[(size_t)row * N + col] = __float2bfloat16(acc[mi][ni][r]);
        }
  } else {
    const int chunk = blockIdx.y * 2 + wn;
    float bv[4];
#pragma unroll
    for (int ni = 0; ni < 4; ni++)
      bv[ni] = bout[col0 + wn * 64 + ni * 16 + l16];
#pragma unroll
    for (int mi = 0; mi < 4; mi++) {
#pragma unroll
      for (int r = 0; r < 4; r++) {
        int row = row0 + wm * 64 + mi * 16 + quad * 4 + r;
        float v0 = acc[mi][0][r] + bv[0];
        float v1 = acc[mi][1][r] + bv[1];
        float v2 = acc[mi][2][r] + bv[2];
        float v3 = acc[mi][3][r] + bv[3];
        int yv = y[row];
        int cb = col0 + wn * 64 + l16;
        if (yv == cb + 0)  logitY[row] = v0;
        if (yv == cb + 16) logitY[row] = v1;
        if (yv == cb + 32) logitY[row] = v2;
        if (yv == cb + 48) logitY[row] = v3;
        float m = fmaxf(fmaxf(v0, v1), fmaxf(v2, v3));
#pragma unroll
        for (int off = 1; off < 16; off <<= 1)
          m = fmaxf(m, __shfl_xor(m, off, 64));
        float s = __expf(v0 - m) + __expf(v1 - m) + __expf(v2 - m) + __expf(v3 - m);
#pragma unroll
        for (int off = 1; off < 16; off <<= 1)
          s += __shfl_xor(s, off, 64);
        if (l16 == 0)
          lse[(size_t)chunk * M_ + row] = make_float2(m, s);
      }
    }
  }
}

// ------------- classifier: 256x256 tile, 8-phase counted-vmcnt schedule -------
// 512 threads = 8 waves (2M x 4N). Per wave: 128x64 output, acc[8][4].
// LDS: dbuf x (A 256x64 + B 256x64) bf16 = 128 KiB -> 1 block/CU forced; declare
// __launch_bounds__(512, 2) (2 waves/SIMD) so the allocator targets <=256 VGPR
// with NO scratch spills (scratch VMEM ops would corrupt the counted vmcnt(N)).
// Same chunk^(row&7) swizzle as k_gemm_bt (linear LDS dest, inverse-swizzled
// global src, swizzled ds_read).
// Iteration i: phases 1-4 compute tile 2i (buf0), 5-8 tile 2i+1 (buf1).
// Stage cadence (region free-times proven by phase read order):
//   ph1: T(2i+1).A1,A3   [buf1 A-high last read prev ph8]
//   ph4: S0.B0,B1 | ph5: S0.B2,B3 [buf0 B free after ph3]
//   ph6: S0.A0,A2 [free after ph3] | ph7: S0.A1,A3 [free after ph4]
//   ph8: S1.B0-3,A0,A2 [buf1 B/A-low free after ph7]   (S0=2i+2, S1=2i+3)
// Waits: ph4 vmcnt(2) -> all of tile 2i+1 landed; ph8 vmcnt(6) -> all of S0.
__global__ __launch_bounds__(512, 2) void k_gemm_cls256(
    const __hip_bfloat16* __restrict__ A, const __hip_bfloat16* __restrict__ Bt,
    int K, const float* __restrict__ bout, const int* __restrict__ y,
    float2* __restrict__ lse, float* __restrict__ logitY) {
  __shared__ __align__(16) __hip_bfloat16 As[2][16384];
  __shared__ __align__(16) __hip_bfloat16 Bs[2][16384];
  const int tid = threadIdx.x;
  const int lane = tid & 63, wave = tid >> 6;
  const int quad = lane >> 4, l16 = lane & 15;
  const int wm = wave >> 2, wn = wave & 3;

  // bijective XCD swizzle (nwg = 16*125 = 2000, divisible by 8); bx fastest so
  // the 16 row-blocks sharing one B panel land on one XCD.
  const int bid = blockIdx.y * 16 + blockIdx.x;
  const int swzb = (bid & 7) * 250 + (bid >> 3);
  const int bx = swzb & 15, by = swzb >> 4;
  const int row0 = bx * 256, col0 = by * 256;

  // staging addressing: m_l = row-in-round, sw = inverse-swizzled k-chunk
  const int m_l = wave * 8 + (lane >> 3);
  const int sw = ((lane & 7) ^ (lane >> 3)) << 3;
  const __hip_bfloat16* Ag = A + (size_t)(row0 + m_l) * K + sw;
  const __hip_bfloat16* Bg = Bt + (size_t)(col0 + m_l) * K + sw;

#define STAGE_A(buf, r, ko)                                                   \
  __builtin_amdgcn_global_load_lds(AS1(Ag + (size_t)(r) * 64 * K + (ko)),     \
                                   AS3(&As[buf][((r) * 64 + wave * 8) * 64]), \
                                   16, 0, 0)
#define STAGE_B(buf, r, ko)                                                   \
  __builtin_amdgcn_global_load_lds(AS1(Bg + (size_t)(r) * 64 * K + (ko)),     \
                                   AS3(&Bs[buf][((r) * 64 + wave * 8) * 64]), \
                                   16, 0, 0)

  // fragment read addressing (row&7 == l16&7 for all fragment rows)
  const int aoff = (wm * 128 + l16) * 64;
  const int boff = (wn * 64 + l16) * 64;
  const int cc0 = ((quad) ^ (l16 & 7)) << 3;
  const int cc1 = ((4 + quad) ^ (l16 & 7)) << 3;

  f32x4 acc[8][4] = {};
  bf16x8 a4[4], b4[4];

#define PH_PRE(buf, cck, mlo, READB)                                          \
  do {                                                                        \
    if (READB) {                                                              \
      _Pragma("unroll") for (int ni = 0; ni < 4; ++ni)                        \
          b4[ni] = *(const bf16x8*)(&Bs[buf][boff + ni * 1024 + (cck)]);      \
    }                                                                         \
    _Pragma("unroll") for (int mi = 0; mi < 4; ++mi)                          \
        a4[mi] = *(const bf16x8*)(&As[buf][aoff + ((mlo) + mi) * 1024 + (cck)]); \
  } while (0)

#define PH_MFMA(mlo)                                                          \
  do {                                                                        \
    __builtin_amdgcn_s_barrier();                                             \
    asm volatile("s_waitcnt lgkmcnt(0)" ::: "memory");                        \
    __builtin_amdgcn_sched_barrier(0);                                        \
    __builtin_amdgcn_s_setprio(1);                                            \
    _Pragma("unroll") for (int mi = 0; mi < 4; ++mi)                          \
        _Pragma("unroll") for (int ni = 0; ni < 4; ++ni)                      \
            acc[(mlo) + mi][ni] = __builtin_amdgcn_mfma_f32_16x16x32_bf16(    \
                a4[mi], b4[ni], acc[(mlo) + mi][ni], 0, 0, 0);                \
    __builtin_amdgcn_s_setprio(0);                                            \
  } while (0)

#define BAR() __builtin_amdgcn_s_barrier()

  // prologue: tile0 fully (8), tile1 all but A1,A3 (6); wait tile0
  STAGE_A(0, 0, 0); STAGE_A(0, 1, 0); STAGE_A(0, 2, 0); STAGE_A(0, 3, 0);
  STAGE_B(0, 0, 0); STAGE_B(0, 1, 0); STAGE_B(0, 2, 0); STAGE_B(0, 3, 0);
  STAGE_B(1, 0, 64); STAGE_B(1, 1, 64); STAGE_B(1, 2, 64); STAGE_B(1, 3, 64);
  STAGE_A(1, 0, 64); STAGE_A(1, 2, 64);
  asm volatile("s_waitcnt vmcnt(6)" ::: "memory");
  BAR();

  // steady iterations 0..6 (tiles 2i, 2i+1; prefetch 2i+2, 2i+3)
  for (int i = 0; i < 7; ++i) {
    const size_t kT1 = (size_t)i * 128 + 64;
    const size_t kS0 = (size_t)i * 128 + 128;
    const size_t kS1 = (size_t)i * 128 + 192;
    // ph1
    PH_PRE(0, cc0, 0, 1);
    STAGE_A(1, 1, kT1); STAGE_A(1, 3, kT1);
    PH_MFMA(0); BAR();
    // ph2
    PH_PRE(0, cc0, 4, 0);
    PH_MFMA(4); BAR();
    // ph3
    PH_PRE(0, cc1, 0, 1);
    PH_MFMA(0); BAR();
    // ph4
    PH_PRE(0, cc1, 4, 0);
    STAGE_B(0, 0, kS0); STAGE_B(0, 1, kS0);
    PH_MFMA(4);
    asm volatile("s_waitcnt vmcnt(2)" ::: "memory");
    BAR();
    // ph5
    PH_PRE(1, cc0, 0, 1);
    STAGE_B(0, 2, kS0); STAGE_B(0, 3, kS0);
    PH_MFMA(0); BAR();
    // ph6
    PH_PRE(1, cc0, 4, 0);
    STAGE_A(0, 0, kS0); STAGE_A(0, 2, kS0);
    PH_MFMA(4); BAR();
    // ph7
    PH_PRE(1, cc1, 0, 1);
    STAGE_A(0, 1, kS0); STAGE_A(0, 3, kS0);
    PH_MFMA(0); BAR();
    // ph8
    PH_PRE(1, cc1, 4, 0);
    STAGE_B(1, 0, kS1); STAGE_B(1, 1, kS1); STAGE_B(1, 2, kS1); STAGE_B(1, 3, kS1);
    STAGE_A(1, 0, kS1); STAGE_A(1, 2, kS1);
    PH_MFMA(4);
    asm volatile("s_waitcnt vmcnt(6)" ::: "memory");
    BAR();
  }
  // tail iteration i=7 (tiles 14,15; only T15.A1,A3 left to stage)
  {
    const size_t kT1 = (size_t)7 * 128 + 64;
    PH_PRE(0, cc0, 0, 1);
    STAGE_A(1, 1, kT1); STAGE_A(1, 3, kT1);
    PH_MFMA(0); BAR();
    PH_PRE(0, cc0, 4, 0);
    PH_MFMA(4); BAR();
    PH_PRE(0, cc1, 0, 1);
    PH_MFMA(0); BAR();
    PH_PRE(0, cc1, 4, 0);
    PH_MFMA(4);
    asm volatile("s_waitcnt vmcnt(0)" ::: "memory");
    BAR();
    PH_PRE(1, cc0, 0, 1);
    PH_MFMA(0); BAR();
    PH_PRE(1, cc0, 4, 0);
    PH_MFMA(4); BAR();
    PH_PRE(1, cc1, 0, 1);
    PH_MFMA(0); BAR();
    PH_PRE(1, cc1, 4, 0);
    PH_MFMA(4);
  }

  // fused LSE epilogue: chunk = 64 output cols per wave; 500 chunks total
  const int chunk = by * 4 + wn;
  float bv[4];
#pragma unroll
  for (int ni = 0; ni < 4; ++ni)
    bv[ni] = bout[col0 + wn * 64 + ni * 16 + l16];
#pragma unroll
  for (int mi = 0; mi < 8; ++mi) {
#pragma unroll
    for (int r = 0; r < 4; ++r) {
      int row = row0 + wm * 128 + mi * 16 + quad * 4 + r;
      float v0 = acc[mi][0][r] + bv[0];
      float v1 = acc[mi][1][r] + bv[1];
      float v2 = acc[mi][2][r] + bv[2];
      float v3 = acc[mi][3][r] + bv[3];
      int yv = y[row];
      int cb = col0 + wn * 64 + l16;
      if (yv == cb + 0)  logitY[row] = v0;
      if (yv == cb + 16) logitY[row] = v1;
      if (yv == cb + 32) logitY[row] = v2;
      if (yv == cb + 48) logitY[row] = v3;
      float m = fmaxf(fmaxf(v0, v1), fmaxf(v2, v3));
#pragma unroll
      for (int off = 1; off < 16; off <<= 1)
        m = fmaxf(m, __shfl_xor(m, off, 64));
      float s = __expf(v0 - m) + __expf(v1 - m) + __expf(v2 - m) + __expf(v3 - m);
#pragma unroll
      for (int off = 1; off < 16; off <<= 1)
        s += __shfl_xor(s, off, 64);
      if (l16 == 0)
        lse[(size_t)chunk * M_ + row] = make_float2(m, s);
    }
  }
#undef STAGE_A
#undef STAGE_B
#undef PH_PRE
#undef PH_MFMA
#undef BAR
}

// ------------- fallback classifier: fp32 B staged through LDS (validated) ---
__global__ __launch_bounds__(256) void k_gemm_cls_f32(
    const __hip_bfloat16* __restrict__ A, const float* __restrict__ B,
    int K, int N, const float* __restrict__ bout, const int* __restrict__ y,
    float2* __restrict__ lse, float* __restrict__ logitY) {
  __shared__ __hip_bfloat16 As[128 * 40];
  __shared__ __hip_bfloat16 Bs[128 * 40];
  const int tid = threadIdx.x;
  const int lane = tid & 63, wave = tid >> 6;
  const int quad = lane >> 4, l16 = lane & 15;
  const int wm = wave & 1, wn = wave >> 1;
  const int row0 = blockIdx.x * 128, col0 = blockIdx.y * 128;
  f32x4 acc[4][4] = {};
  const int a_m = tid >> 1, a_k = (tid & 1) << 4;
  const int b_k = tid >> 3, b_n = (tid & 7) << 4;
  for (int k0 = 0; k0 < K; k0 += 32) {
    const uint4* ap = (const uint4*)(A + (size_t)(row0 + a_m) * K + k0 + a_k);
    uint4 av0 = ap[0];
    uint4 av1 = ap[1];
    const float* bp = B + (size_t)(k0 + b_k) * N + col0 + b_n;
    float4 bv0 = *(const float4*)(bp + 0);
    float4 bv1 = *(const float4*)(bp + 4);
    float4 bv2 = *(const float4*)(bp + 8);
    float4 bv3 = *(const float4*)(bp + 12);
    __syncthreads();
    *(uint4*)(As + a_m * 40 + a_k) = av0;
    *(uint4*)(As + a_m * 40 + a_k + 8) = av1;
    {
      float tmp[16] = {bv0.x, bv0.y, bv0.z, bv0.w, bv1.x, bv1.y, bv1.z, bv1.w,
                       bv2.x, bv2.y, bv2.z, bv2.w, bv3.x, bv3.y, bv3.z, bv3.w};
#pragma unroll
      for (int j = 0; j < 16; j++)
        Bs[(b_n + j) * 40 + b_k] = __float2bfloat16(tmp[j]);
    }
    __syncthreads();
    bf16x8 af[4], bfr[4];
#pragma unroll
    for (int mi = 0; mi < 4; mi++)
      af[mi] = *(const bf16x8*)(As + (wm * 64 + mi * 16 + l16) * 40 + quad * 8);
#pragma unroll
    for (int ni = 0; ni < 4; ni++)
      bfr[ni] = *(const bf16x8*)(Bs + (wn * 64 + ni * 16 + l16) * 40 + quad * 8);
#pragma unroll
    for (int mi = 0; mi < 4; mi++)
#pragma unroll
      for (int ni = 0; ni < 4; ni++)
        acc[mi][ni] = __builtin_amdgcn_mfma_f32_16x16x32_bf16(af[mi], bfr[ni],
                                                              acc[mi][ni], 0, 0, 0);
  }
  const int chunk = blockIdx.y * 2 + wn;
  float bv[4];
#pragma unroll
  for (int ni = 0; ni < 4; ni++)
    bv[ni] = bout[col0 + wn * 64 + ni * 16 + l16];
#pragma unroll
  for (int mi = 0; mi < 4; mi++) {
#pragma unroll
    for (int r = 0; r < 4; r++) {
      int row = row0 + wm * 64 + mi * 16 + quad * 4 + r;
      float v0 = acc[mi][0][r] + bv[0];
      float v1 = acc[mi][1][r] + bv[1];
      float v2 = acc[mi][2][r] + bv[2];
      float v3 = acc[mi][3][r] + bv[3];
      int yv = y[row];
      int cb = col0 + wn * 64 + l16;
      if (yv == cb + 0)  logitY[row] = v0;
      if (yv == cb + 16) logitY[row] = v1;
      if (yv == cb + 32) logitY[row] = v2;
      if (yv == cb + 48) logitY[row] = v3;
      float m = fmaxf(fmaxf(v0, v1), fmaxf(v2, v3));
#pragma unroll
      for (int off = 1; off < 16; off <<= 1)
        m = fmaxf(m, __shfl_xor(m, off, 64));
      float s = __expf(v0 - m) + __expf(v1 - m) + __expf(v2 - m) + __expf(v3 - m);
#pragma unroll
      for (int off = 1; off < 16; off <<= 1)
        s += __shfl_xor(s, off, 64);
      if (l16 == 0)
        lse[(size_t)chunk * M_ + row] = make_float2(m, s);
    }
  }
}

// ---------------- flash-style MFMA attention ----------------
__global__ __launch_bounds__(256) void k_attn_mfma(
    const __hip_bfloat16* __restrict__ z, const __hip_bfloat16* __restrict__ kv,
    __hip_bfloat16* __restrict__ ao, const float* __restrict__ alpha_p) {
  __shared__ __hip_bfloat16 Qs[64 * 40];
  __shared__ __hip_bfloat16 Ks[128 * 40];
  __shared__ __hip_bfloat16 Vt[32 * 136];
  __shared__ __hip_bfloat16 Ps[64 * 136];
  const int tid = threadIdx.x;
  const int lane = tid & 63, wave = tid >> 6;
  const int quad = lane >> 4, l16 = lane & 15;
  const int bh = blockIdx.y, b = bh >> 3, h = bh & 7;
  const int q0 = blockIdx.x * 64;
  const float scale = 0.17677669529663687f;  // 32^-0.5

  {
    int r = tid >> 2, c = (tid & 3) << 3;
    *(uint4*)(Qs + r * 40 + c) =
        *(const uint4*)(z + ((size_t)(q0 + r) * B_ + b) * PROJ_ + h * 32 + c);
  }

  float m_i[4] = {-1e30f, -1e30f, -1e30f, -1e30f};
  float l_i[4] = {0.f, 0.f, 0.f, 0.f};
  f32x4 o_acc[2] = {};

  const int ntile = (q0 + 191) >> 7;

  for (int t = 0; t < ntile; t++) {
    const int s0 = t << 7;
    __syncthreads();
    {
      int r = tid >> 1, c = (tid & 1) << 4;
      const uint4* kp =
          (const uint4*)(kv + ((size_t)(s0 + r) * B_ + b) * 512 + h * 32 + c);
      *(uint4*)(Ks + r * 40 + c) = kp[0];
      *(uint4*)(Ks + r * 40 + c + 8) = kp[1];
    }
    {
      int s = tid >> 1, dbase = (tid & 1) << 4;
      const __hip_bfloat16* vp =
          kv + ((size_t)(s0 + s) * B_ + b) * 512 + 256 + h * 32 + dbase;
      union { uint4 u; __hip_bfloat16 e[8]; } t0, t1;
      t0.u = *(const uint4*)vp;
      t1.u = *(const uint4*)(vp + 8);
#pragma unroll
      for (int j = 0; j < 8; j++) {
        Vt[(dbase + j) * 136 + s] = t0.e[j];
        Vt[(dbase + 8 + j) * 136 + s] = t1.e[j];
      }
    }
    __syncthreads();

    f32x4 sacc[8] = {};
    {
      bf16x8 aq = *(const bf16x8*)(Qs + (wave * 16 + l16) * 40 + quad * 8);
#pragma unroll
      for (int ni = 0; ni < 8; ni++) {
        bf16x8 bk = *(const bf16x8*)(Ks + (ni * 16 + l16) * 40 + quad * 8);
        sacc[ni] = __builtin_amdgcn_mfma_f32_16x16x32_bf16(aq, bk, sacc[ni], 0, 0, 0);
      }
    }

#pragma unroll
    for (int r = 0; r < 4; r++) {
      const int qrow = q0 + wave * 16 + quad * 4 + r;
      float mx = -1e30f;
#pragma unroll
      for (int ni = 0; ni < 8; ni++) {
        int s = s0 + ni * 16 + l16;
        float v = (s <= qrow) ? sacc[ni][r] * scale : -1e30f;
        sacc[ni][r] = v;
        mx = fmaxf(mx, v);
      }
#pragma unroll
      for (int off = 1; off < 16; off <<= 1)
        mx = fmaxf(mx, __shfl_xor(mx, off, 64));
      float mnew = fmaxf(m_i[r], mx);
      float al = __expf(m_i[r] - mnew);
      m_i[r] = mnew;
      float ps = 0.f;
#pragma unroll
      for (int ni = 0; ni < 8; ni++) {
        float p = __expf(sacc[ni][r] - mnew);
        Ps[(wave * 16 + quad * 4 + r) * 136 + ni * 16 + l16] = __float2bfloat16(p);
        ps += p;
      }
#pragma unroll
      for (int off = 1; off < 16; off <<= 1)
        ps += __shfl_xor(ps, off, 64);
      l_i[r] = l_i[r] * al + ps;
      o_acc[0][r] *= al;
      o_acc[1][r] *= al;
    }

#pragma unroll
    for (int ks = 0; ks < 4; ks++) {
      bf16x8 ap = *(const bf16x8*)(Ps + (wave * 16 + l16) * 136 + ks * 32 + quad * 8);
#pragma unroll
      for (int ni = 0; ni < 2; ni++) {
        bf16x8 bv = *(const bf16x8*)(Vt + (ni * 16 + l16) * 136 + ks * 32 + quad * 8);
        o_acc[ni] = __builtin_amdgcn_mfma_f32_16x16x32_bf16(ap, bv, o_acc[ni], 0, 0, 0);
      }
    }
  }

  const float arz = alpha_p[0];
#pragma unroll
  for (int ni = 0; ni < 2; ni++)
#pragma unroll
    for (int r = 0; r < 4; r++) {
      int row = q0 + wave * 16 + quad * 4 + r;
      size_t oi = ((size_t)row * B_ + b) * PROJ_ + h * 32 + ni * 16 + l16;
      float res = __bfloat162float(z[oi]);
      ao[oi] = __float2bfloat16(o_acc[ni][r] / l_i[r] * arz + res);
    }
}

// ------------- SRU: 64 blocks x 64 thr, 8-step register prefetch chunks -------
__global__ __launch_bounds__(64) void k_sru(const __hip_bfloat16* __restrict__ U,
                                            __hip_bfloat16* __restrict__ h,
                                            const float* __restrict__ hidden,
                                            const float* __restrict__ wc,
                                            const float* __restrict__ bias) {
  int tid = blockIdx.x * 64 + threadIdx.x;  // 0..4095
  int b = tid >> 10, d = tid & 1023;
  float vf = wc[d], vr = wc[D_ + d];
  float bfs = bias[d], brs = bias[D_ + d];
  float c = hidden[b * D_ + d];
  const __hip_bfloat16* up = U + (size_t)b * 3 * D_ + 3 * d;
  __hip_bfloat16* hp = h + (size_t)b * D_ + d;
  const int US = B_ * 3 * D_, HS = B_ * D_;
  for (int l0 = 0; l0 < L_; l0 += 8) {
    float u0[8], u1[8], u2[8], rs[8];
#pragma unroll
    for (int j = 0; j < 8; j++) {
      u0[j] = __bfloat162float(up[(size_t)j * US + 0]);
      u1[j] = __bfloat162float(up[(size_t)j * US + 1]);
      u2[j] = __bfloat162float(up[(size_t)j * US + 2]);
      rs[j] = __bfloat162float(hp[(size_t)j * HS]);
    }
#pragma unroll
    for (int j = 0; j < 8; j++) {
      float f = __builtin_amdgcn_rcpf(1.f + __expf(-(u1[j] + bfs + vf * c)));
      c = u0[j] + f * (c - u0[j]);
      float r = __builtin_amdgcn_rcpf(1.f + __expf(-(u2[j] + brs + vr * c)));
      hp[(size_t)j * HS] = __float2bfloat16(rs[j] + r * (c - rs[j]));
    }
    up += (size_t)8 * US;
    hp += (size_t)8 * HS;
  }
}

// ---------------- finalize: combine chunk partials -> fp32 loss ----------------
__global__ __launch_bounds__(256) void k_finalize(const float2* __restrict__ lse,
                                                  const float* __restrict__ logitY,
                                                  float* __restrict__ out) {
  int row = blockIdx.x * 256 + threadIdx.x;
  float M = -1e30f, S = 0.f;
  for (int c = 0; c < V_ / 64; c++) {
    float2 p = lse[(size_t)c * M_ + row];
    if (p.x > M) {
      S = S * __expf(M - p.x) + p.y;
      M = p.x;
    } else {
      S += p.y * __expf(p.x - M);
    }
  }
  out[row] = M + logf(S) - logitY[row];
}

extern "C" void kernel_launch(void* const* d_in, const int* in_sizes, int n_in,
                              void* d_out, int out_size, void* d_ws, size_t ws_size,
                              hipStream_t stream) {
  const int* x = (const int*)d_in[0];
  const int* y = (const int*)d_in[1];
  const float* hidden = (const float*)d_in[2];
  const float* emb = (const float*)d_in[3];
  const float* W1 = (const float*)d_in[4];
  const float* W2 = (const float*)d_in[5];
  const float* W3 = (const float*)d_in[6];
  const float* alpha = (const float*)d_in[7];
  const float* wc = (const float*)d_in[8];
  const float* bias = (const float*)d_in[9];
  const float* Wout = (const float*)d_in[10];
  const float* bout = (const float*)d_in[11];

  char* ws = (char*)d_ws;
  __hip_bfloat16* h16  = (__hip_bfloat16*)(ws + 0);          // 8 MB
  __hip_bfloat16* z16  = (__hip_bfloat16*)(ws + 8388608);    // 2 MB
  __hip_bfloat16* kv16 = (__hip_bfloat16*)(ws + 10485760);   // 4 MB
  __hip_bfloat16* ao16 = (__hip_bfloat16*)(ws + 14680064);   // 2 MB
  __hip_bfloat16* W1t  = (__hip_bfloat16*)(ws + 16777216);   // 2 MB  [4][256][1024]
  __hip_bfloat16* W2t  = (__hip_bfloat16*)(ws + 18874368);   // 1 MB  [4][512][256]
  __hip_bfloat16* W3t  = (__hip_bfloat16*)(ws + 19922944);   // 6 MB  [4][3072][256]
  __hip_bfloat16* U16  = (__hip_bfloat16*)(ws + 26214400);   // 24 MB
  const bool fast = ws_size >= 109723648ull;
  __hip_bfloat16* Woutt = (__hip_bfloat16*)(ws + 26214400);  // 64 MB [32000][1024]
  float2* lse    = (float2*)(ws + (fast ? 93323264u : 26214400u));  // 16 MB
  float* logitY  = (float*)(ws + (fast ? 109707264u : 42598400u));  // 16 KB
  float* out     = (float*)d_out;

  k_embed<<<4096, 256, 0, stream>>>(x, emb, h16);
  k_transpose<<<dim3(4, 16, 4), 256, 0, stream>>>(W1, W1t, D_, PROJ_,
                                                  (long)D_ * PROJ_, (long)PROJ_ * D_);
  k_transpose<<<dim3(8, 4, 4), 256, 0, stream>>>(W2, W2t, PROJ_, 2 * PROJ_,
                                                 (long)PROJ_ * 2 * PROJ_,
                                                 (long)2 * PROJ_ * PROJ_);
  k_transpose<<<dim3(48, 4, 4), 256, 0, stream>>>(W3, W3t, PROJ_, 3 * D_,
                                                  (long)PROJ_ * 3 * D_,
                                                  (long)3 * D_ * PROJ_);
  for (int i = 0; i < 4; i++) {
    k_gemm_bt<false><<<dim3(32, 2), 256, 0, stream>>>(
        h16, W1t + (size_t)i * PROJ_ * D_, z16, D_, PROJ_,
        nullptr, nullptr, nullptr, nullptr);
    k_gemm_bt<false><<<dim3(32, 4), 256, 0, stream>>>(
        z16, W2t + (size_t)i * 2 * PROJ_ * PROJ_, kv16, PROJ_, 2 * PROJ_,
        nullptr, nullptr, nullptr, nullptr);
    k_attn_mfma<<<dim3(16, 32), 256, 0, stream>>>(z16, kv16, ao16, alpha + i);
    k_gemm_bt<false><<<dim3(32, 24), 256, 0, stream>>>(
        ao16, W3t + (size_t)i * 3 * D_ * PROJ_, U16, PROJ_, 3 * D_,
        nullptr, nullptr, nullptr, nullptr);
    k_sru<<<64, 64, 0, stream>>>(U16, h16, hidden + (size_t)i * B_ * D_,
                                 wc + (size_t)i * 2 * D_, bias + (size_t)i * 2 * D_);
  }
  if (fast) {
    k_transpose<<<dim3(500, 16, 1), 256, 0, stream>>>(Wout, Woutt, D_, V_, 0, 0);
    k_gemm_cls256<<<dim3(16, 125), 512, 0, stream>>>(h16, Woutt, D_, bout, y,
                                                     lse, logitY);
  } else {
    k_gemm_cls_f32<<<dim3(32, V_ / 128), 256, 0, stream>>>(
        h16, Wout, D_, V_, bout, y, lse, logitY);
  }
  k_finalize<<<16, 256, 0, stream>>>(lse, logitY, out);
}